// Round 2
// baseline (1016.114 us; speedup 1.0000x reference)
//
#include <hip/hip_runtime.h>
#include <hip/hip_fp16.h>

#define B_  32
#define L_  2048
#define U_  512
#define H_  8
#define HD_ 64

typedef __attribute__((ext_vector_type(8))) _Float16 half8;
typedef __attribute__((ext_vector_type(4))) float f32x4;

// monotonic float->uint map for atomic max (works for negatives)
__device__ __forceinline__ unsigned fmap(float x) {
    unsigned u = __float_as_uint(x);
    return (u & 0x80000000u) ? ~u : (u | 0x80000000u);
}
__device__ __forceinline__ float funmap(unsigned m) {
    unsigned bits = (m & 0x80000000u) ? (m ^ 0x80000000u) : ~m;
    return __uint_as_float(bits);
}

// read 8 consecutive fp32 from LDS, convert to fp16x8 MFMA fragment
__device__ __forceinline__ half8 ldsfrag(const char* p) {
    const f32x4 x = *(const f32x4*)p;
    const f32x4 y = *(const f32x4*)(p + 16);
    auto h0 = __builtin_amdgcn_cvt_pkrtz(x[0], x[1]);
    auto h1 = __builtin_amdgcn_cvt_pkrtz(x[2], x[3]);
    auto h2 = __builtin_amdgcn_cvt_pkrtz(y[0], y[1]);
    auto h3 = __builtin_amdgcn_cvt_pkrtz(y[2], y[3]);
    half8 r;
    r[0] = h0[0]; r[1] = h0[1]; r[2] = h1[0]; r[3] = h1[1];
    r[4] = h2[0]; r[5] = h2[1]; r[6] = h3[0]; r[7] = h3[1];
    return r;
}

// ---------------------------------------------------------------------------
// Kernel 1: repack [Wq;Wk;Wv] (O,I,3) fp32 into tile-blocked, chunk-swizzled A.
// Layout: Wrp[mblk][kk][iblk][m(128)][chunk(8)][e(8)] fp32; stored chunk c_st
// (32 B = 8 floats) holds logical chunk c_st ^ (m&7)  (LDS bank swizzle).
// ---------------------------------------------------------------------------
__global__ void repack_w(const float* __restrict__ Wq,
                         const float* __restrict__ Wk,
                         const float* __restrict__ Wv,
                         float* __restrict__ Wrp) {
    int id = blockIdx.x * 256 + threadIdx.x;       // 2,359,296 total
    int e    = id & 7;
    int c_st = (id >> 3) & 7;
    int m    = (id >> 6) & 127;
    int blk  = id >> 13;                           // (mblk*3+kk)*8+iblk
    int iblk = blk & 7;
    int kk   = (blk >> 3) % 3;
    int mblk = blk / 24;
    int o = mblk * 128 + m;
    const float* W = (o < 512) ? Wq : (o < 1024) ? Wk : Wv;
    int ol = o & 511;
    int ig = iblk * 64 + ((c_st ^ (m & 7)) << 3) + e;
    Wrp[id] = W[(ol * 512 + ig) * 3 + kk];
}

// ---------------------------------------------------------------------------
// Kernel 2: fused conv1d(K=3) GEMM  C[o,(b,l)] = sum_{i,kk} W[o,i,kk]*t[b,l+kk-1,i]
//  M=1536 (q|k|v), N=65536, K=512 x 3 taps. 128x128 tile, BK=64, 4 waves.
//  fp32 staged in LDS, converted to fp16 fragments in-register.
//  Epilogue: +bias; q -> atomic max only; k/v -> fp16 store + atomic max.
// ---------------------------------------------------------------------------
__global__ void __launch_bounds__(256) conv_gemm(
    const float* __restrict__ t,      // fp32 (B,L,U)
    const float* __restrict__ Wrp,
    const float* __restrict__ bq,
    const float* __restrict__ bk,
    const float* __restrict__ bv,
    __half* __restrict__ kbuf, __half* __restrict__ vbuf,
    unsigned* __restrict__ qmaxU, unsigned* __restrict__ kmaxU,
    unsigned* __restrict__ vmaxU) {
    __shared__ float lA[128 * 64];   // [m][i] rows of 256B, 32B-chunk swizzled
    __shared__ float lB[128 * 64];   // [n][i] rows of 256B, 32B-chunk swizzled

    const int tid  = threadIdx.x;
    const int lane = tid & 63;
    const int w    = tid >> 6;
    const int wm = w >> 1, wn = w & 1;
    const int bid   = blockIdx.x;
    const int mblk  = bid % 12;
    const int ntile = bid / 12;
    const int bb = ntile >> 4;
    const int l0 = (ntile & 15) << 7;
    const int lane15 = lane & 15, kgrp = lane >> 4;

    f32x4 acc[4][4];
#pragma unroll
    for (int a = 0; a < 4; ++a)
#pragma unroll
        for (int c = 0; c < 4; ++c) acc[a][c] = (f32x4){0.f, 0.f, 0.f, 0.f};

    for (int iter = 0; iter < 24; ++iter) {
        const int kk   = iter >> 3;
        const int iblk = iter & 7;
        // ---- stage A (weights): contiguous 32 KB block ----
        const char* srcA =
            (const char*)(Wrp + (((size_t)(mblk * 3 + kk) * 8 + iblk) << 13));
#pragma unroll
        for (int s = 0; s < 8; ++s) {
            int base = s * 4096 + w * 1024;            // wave-uniform LDS base
            __builtin_amdgcn_global_load_lds(
                (const __attribute__((address_space(1))) unsigned int*)(srcA + base + lane * 16),
                (__attribute__((address_space(3))) unsigned int*)((char*)lA + base),
                16, 0, 0);
        }
        // ---- stage B (activations): rows = l-positions, swizzled 32B chunks ----
        const int i0 = iblk << 6;
#pragma unroll
        for (int s = 0; s < 8; ++s) {
            int base = s * 4096 + w * 1024;            // wave-uniform LDS base
            int off  = base + lane * 16;
            int n    = off >> 8;                       // 256 B per row
            int p16  = (off >> 4) & 15;                // 16B piece within row
            int c_st = p16 >> 1;                       // 32B chunk
            int half = p16 & 1;
            int l    = l0 + n + kk - 1;
            if (l >= 0 && l < L_) {
                const char* g = (const char*)t +
                    ((((size_t)bb * L_ + l) * U_ + i0) << 2) +
                    (((c_st ^ (n & 7)) << 5) | (half << 4));
                __builtin_amdgcn_global_load_lds(
                    (const __attribute__((address_space(1))) unsigned int*)g,
                    (__attribute__((address_space(3))) unsigned int*)((char*)lB + base),
                    16, 0, 0);
            } else {   // conv zero padding row
                uint4 z; z.x = z.y = z.z = z.w = 0u;
                *(uint4*)((char*)lB + off) = z;
            }
        }
        __syncthreads();
        // ---- compute: 32 MFMA (2 k-slices of 32) ----
#pragma unroll
        for (int ks = 0; ks < 2; ++ks) {
            const int c = ks * 4 + kgrp;               // logical 32B chunk
            half8 af[4], bfr[4];
#pragma unroll
            for (int mi = 0; mi < 4; ++mi) {
                int r = wm * 64 + mi * 16 + lane15;
                af[mi] = ldsfrag((const char*)lA + r * 256 + ((c ^ (r & 7)) << 5));
            }
#pragma unroll
            for (int ni = 0; ni < 4; ++ni) {
                int n = wn * 64 + ni * 16 + lane15;
                bfr[ni] = ldsfrag((const char*)lB + n * 256 + ((c ^ (n & 7)) << 5));
            }
#pragma unroll
            for (int mi = 0; mi < 4; ++mi)
#pragma unroll
                for (int ni = 0; ni < 4; ++ni)
                    acc[mi][ni] = __builtin_amdgcn_mfma_f32_16x16x32_f16(
                        af[mi], bfr[ni], acc[mi][ni], 0, 0, 0);
        }
        __syncthreads();
    }

    // ---- epilogue ----
    const int mat = mblk >> 2;                         // 0=q 1=k 2=v
    const float* bias = (mat == 0) ? bq : (mat == 1) ? bk : bv;
    const int oBase = ((mblk & 3) << 7) + wm * 64 + kgrp * 4;
#pragma unroll
    for (int mi = 0; mi < 4; ++mi) {
#pragma unroll
        for (int r = 0; r < 4; ++r) {
            const int o = oBase + mi * 16 + r;         // channel within matrix
            const float bsv = bias[o];
            float vals[4];
            float mx = -3.0e38f;
#pragma unroll
            for (int ni = 0; ni < 4; ++ni) {
                float v = acc[mi][ni][r] + bsv;
                vals[ni] = v;
                mx = fmaxf(mx, v);
            }
#pragma unroll
            for (int d = 1; d < 16; d <<= 1) mx = fmaxf(mx, __shfl_xor(mx, d, 64));
            if (mat == 0) {
                if (lane15 == 0) atomicMax(&qmaxU[bb * U_ + o], fmap(mx));
            } else {
                __half* buf = (mat == 1) ? kbuf : vbuf;
                size_t rowbase = ((size_t)bb * U_ + o) * L_ + l0 + wn * 64;
#pragma unroll
                for (int ni = 0; ni < 4; ++ni)
                    buf[rowbase + ni * 16 + lane15] = __float2half(vals[ni]);
                unsigned* mptr = (mat == 1) ? kmaxU : vmaxU;
                if (lane15 == 0) atomicMax(&mptr[bb * U_ + o], fmap(mx));
            }
        }
    }
}

// ---------------------------------------------------------------------------
// Kernel 3: per-(b,h) attention: on-the-fly maxpool3 of k,v + masked softmax
// over 2049 keys (global key from kmax/vmax), output (B,H,HD) fp32.
// ---------------------------------------------------------------------------
__global__ void __launch_bounds__(256) attn_kernel(
    const __half* __restrict__ kbuf, const __half* __restrict__ vbuf,
    const unsigned* __restrict__ qmaxU, const unsigned* __restrict__ kmaxU,
    const unsigned* __restrict__ vmaxU,
    const int* __restrict__ g_mask, const int* __restrict__ t_mask,
    float* __restrict__ attout) {
    const int bh = blockIdx.x;
    const int b = bh >> 3, h = bh & 7;
    const int tid = threadIdx.x;
    __shared__ float qs[64], kg[64], vg[64];
    __shared__ float pl[2048];
    __shared__ float red[256];
    if (tid < 64) {
        qs[tid] = funmap(qmaxU[b * U_ + h * 64 + tid]);
        kg[tid] = funmap(kmaxU[b * U_ + h * 64 + tid]);
        vg[tid] = funmap(vmaxU[b * U_ + h * 64 + tid]);
    }
    __syncthreads();
    const float scale = 0.044194173824159216f;   // 1/sqrt(512)

    // logits for the 2048 local (pooled) keys; thread owns 8 positions
    const __half* kbase = kbuf + ((size_t)b * U_ + h * 64) * L_;
    const int l0 = tid * 8;
    float acc[8];
#pragma unroll
    for (int j = 0; j < 8; ++j) acc[j] = 0.f;
    for (int o = 0; o < 64; ++o) {
        const __half* row = kbase + (size_t)o * L_;
        union { uint4 u; __half hh[8]; } pk;
        pk.u = *(const uint4*)(row + l0);
        float f[10];
#pragma unroll
        for (int j = 0; j < 8; ++j) f[j + 1] = __half2float(pk.hh[j]);
        f[0] = (l0 == 0) ? -3.0e38f : __half2float(row[l0 - 1]);
        f[9] = (l0 + 8 >= L_) ? -3.0e38f : __half2float(row[l0 + 8]);
        const float qw = qs[o];
#pragma unroll
        for (int j = 0; j < 8; ++j)
            acc[j] += qw * fmaxf(f[j], fmaxf(f[j + 1], f[j + 2]));
    }
    float lmax = -3.0e38f;
#pragma unroll
    for (int j = 0; j < 8; ++j) {
        int tm = t_mask[b * L_ + l0 + j];
        float lg = (tm == 0) ? -INFINITY : acc[j] * scale;
        pl[l0 + j] = lg;
        lmax = fmaxf(lmax, lg);
    }
    // global-key logit (redundantly on all threads; cheap)
    float ag = 0.f;
    for (int d = 0; d < 64; ++d) ag += qs[d] * kg[d];
    const int gm = g_mask[b];
    float lgg = gm ? ag * scale : -INFINITY;
    // block max
    red[tid] = lmax; __syncthreads();
    for (int s = 128; s > 0; s >>= 1) {
        if (tid < s) red[tid] = fmaxf(red[tid], red[tid + s]);
        __syncthreads();
    }
    float mx = fmaxf(red[0], lgg);
    __syncthreads();
    // exponentials + denominator
    float lsum = 0.f;
#pragma unroll
    for (int j = 0; j < 8; ++j) {
        float lg = pl[l0 + j];
        float e = (lg <= -3.0e38f) ? 0.f : __expf(lg - mx);
        pl[l0 + j] = e;
        lsum += e;
    }
    red[tid] = lsum; __syncthreads();
    for (int s = 128; s > 0; s >>= 1) {
        if (tid < s) red[tid] += red[tid + s];
        __syncthreads();
    }
    float eg = gm ? __expf(lgg - mx) : 0.f;
    float den = red[0] + eg;
    if (!(den > 0.f)) den = 1.f;
    __syncthreads();
    // weighted sum of pooled values: thread = (o = tid/4, chunk = tid%4 of 512 l's)
    const int o = tid >> 2;
    const int ch = tid & 3;
    const __half* vrow = vbuf + ((size_t)b * U_ + h * 64 + o) * L_;
    float s = 0.f;
    for (int lb = ch * 512; lb < ch * 512 + 512; lb += 8) {
        union { uint4 u; __half hh[8]; } pk;
        pk.u = *(const uint4*)(vrow + lb);
        float f[10];
#pragma unroll
        for (int j = 0; j < 8; ++j) f[j + 1] = __half2float(pk.hh[j]);
        f[0] = (lb == 0) ? -3.0e38f : __half2float(vrow[lb - 1]);
        f[9] = (lb + 8 >= L_) ? -3.0e38f : __half2float(vrow[lb + 8]);
#pragma unroll
        for (int j = 0; j < 8; ++j)
            s += pl[lb + j] * fmaxf(f[j], fmaxf(f[j + 1], f[j + 2]));
    }
    red[tid] = s; __syncthreads();
    if (ch == 0) {
        float tot = red[tid] + red[tid + 1] + red[tid + 2] + red[tid + 3];
        float val = (eg * vg[o] + tot) / den;
        val *= (float)gm;
        attout[(size_t)b * U_ + h * 64 + o] = val;
    }
}

// ---------------------------------------------------------------------------
// Kernel 4: head mix (H x H) + output projection (U x U), out fp32 (B,1,U)
// ---------------------------------------------------------------------------
__global__ void __launch_bounds__(512) out_kernel(
    const float* __restrict__ attout,
    const float* __restrict__ Wh, const float* __restrict__ bh,
    const float* __restrict__ Wo, const float* __restrict__ bo,
    float* __restrict__ out) {
    const int b = blockIdx.x;
    const int tid = threadIdx.x;
    __shared__ float tmp[512];
    const int oh = tid >> 6, d = tid & 63;
    float s = bh[oh];
#pragma unroll
    for (int i = 0; i < 8; ++i)
        s += Wh[oh * 8 + i] * attout[b * U_ + i * 64 + d];
    tmp[oh * 64 + d] = s;          // u = h*64 + d
    __syncthreads();
    float s2 = bo[tid];
    const float* wrow = Wo + tid * 512;
    for (int i = 0; i < 512; ++i) s2 += wrow[i] * tmp[i];
    out[b * U_ + tid] = s2;
}

// ---------------------------------------------------------------------------
extern "C" void kernel_launch(void* const* d_in, const int* in_sizes, int n_in,
                              void* d_out, int out_size, void* d_ws, size_t ws_size,
                              hipStream_t stream) {
    const float* t  = (const float*)d_in[0];
    // d_in[1] = g : unused by the reference
    const int* g_mask = (const int*)d_in[2];
    const int* t_mask = (const int*)d_in[3];
    const float* Wq = (const float*)d_in[4];
    const float* bq = (const float*)d_in[5];
    const float* Wk = (const float*)d_in[6];
    const float* bk = (const float*)d_in[7];
    const float* Wv = (const float*)d_in[8];
    const float* bv = (const float*)d_in[9];
    const float* Wh = (const float*)d_in[10];
    const float* bh = (const float*)d_in[11];
    const float* Wo = (const float*)d_in[12];
    const float* bo = (const float*)d_in[13];

    char* ws = (char*)d_ws;
    float* Wrp = (float*)ws;                                         // 9,437,184 B
    __half* kbuf = (__half*)(ws + 9437184);                          // 67,108,864 B
    __half* vbuf = (__half*)(ws + 9437184 + 67108864);               // 67,108,864 B
    unsigned* qmaxU = (unsigned*)(ws + 9437184 + 2 * 67108864);      // 64 KB
    unsigned* kmaxU = qmaxU + 16384;
    unsigned* vmaxU = kmaxU + 16384;
    float* attout = (float*)(vmaxU + 16384);                         // 64 KB

    hipMemsetAsync(qmaxU, 0, 3 * 16384 * sizeof(unsigned), stream);
    repack_w<<<9216, 256, 0, stream>>>(Wq, Wk, Wv, Wrp);
    conv_gemm<<<6144, 256, 0, stream>>>(t, Wrp, bq, bk, bv, kbuf, vbuf,
                                        qmaxU, kmaxU, vmaxU);
    attn_kernel<<<256, 256, 0, stream>>>(kbuf, vbuf, qmaxU, kmaxU, vmaxU,
                                         g_mask, t_mask, attout);
    out_kernel<<<32, 512, 0, stream>>>(attout, Wh, bh, Wo, bo, (float*)d_out);
}

// Round 4
// 1006.552 us; speedup vs baseline: 1.0095x; 1.0095x over previous
//
#include <hip/hip_runtime.h>
#include <hip/hip_fp16.h>

#define B_  32
#define L_  2048
#define U_  512
#define H_  8
#define HD_ 64

typedef __attribute__((ext_vector_type(8))) _Float16 half8;
typedef __attribute__((ext_vector_type(4))) float f32x4;

// monotonic float->uint map for atomic max (works for negatives)
__device__ __forceinline__ unsigned fmap(float x) {
    unsigned u = __float_as_uint(x);
    return (u & 0x80000000u) ? ~u : (u | 0x80000000u);
}
__device__ __forceinline__ float funmap(unsigned m) {
    unsigned bits = (m & 0x80000000u) ? (m ^ 0x80000000u) : ~m;
    return __uint_as_float(bits);
}

// ---------------------------------------------------------------------------
// Kernel 1: repack [Wq;Wk;Wv] (O,I,3) fp32 -> fp16 tile-blocked, chunk-swizzled.
// Layout: Wrp[mblk][kk][iblk][m(128)][chunk(8)][e(8)] fp16; stored 16B chunk
// c_st holds logical chunk c_st ^ (m&7)  (LDS bank swizzle).
// ---------------------------------------------------------------------------
__global__ void repack_w(const float* __restrict__ Wq,
                         const float* __restrict__ Wk,
                         const float* __restrict__ Wv,
                         __half* __restrict__ Wrp) {
    int id = blockIdx.x * 256 + threadIdx.x;       // 2,359,296 total
    int e    = id & 7;
    int c_st = (id >> 3) & 7;
    int m    = (id >> 6) & 127;
    int blk  = id >> 13;                           // (mblk*3+kk)*8+iblk
    int iblk = blk & 7;
    int kk   = (blk >> 3) % 3;
    int mblk = blk / 24;
    int o = mblk * 128 + m;
    const float* W = (o < 512) ? Wq : (o < 1024) ? Wk : Wv;
    int ol = o & 511;
    int ig = iblk * 64 + ((c_st ^ (m & 7)) << 3) + e;
    Wrp[id] = __float2half(W[(ol * 512 + ig) * 3 + kk]);
}

// ---------------------------------------------------------------------------
// Kernel 2: fused conv1d(K=3) GEMM  C[o,(b,l)] = sum_{i,kk} W[o,i,kk]*t[b,l+kk-1,i]
//  M=1536 (q|k|v), N=65536, K=512 x 3 taps. 128x128 tile, BK=64, 4 waves.
//  A: fp16 via global_load_lds.  B: fp32 global -> cvt -> fp16 ds_write.
//  LDS 32KB/block. XCD-aware block swizzle for B-tile L2 reuse.
//  Epilogue: +bias; q -> atomic max only; k/v -> fp16 store + atomic max.
// ---------------------------------------------------------------------------
__global__ void __launch_bounds__(256) conv_gemm(
    const float* __restrict__ t,      // fp32 (B,L,U)
    const __half* __restrict__ Wrp,
    const float* __restrict__ bq,
    const float* __restrict__ bk,
    const float* __restrict__ bv,
    __half* __restrict__ kbuf, __half* __restrict__ vbuf,
    unsigned* __restrict__ qmaxU, unsigned* __restrict__ kmaxU,
    unsigned* __restrict__ vmaxU) {
    __shared__ _Float16 lA[128 * 64];   // 16 KB: [m][i], 128B rows, 16B-chunk swizzle
    __shared__ _Float16 lB[128 * 64];   // 16 KB: [n][i], 128B rows, 16B-chunk swizzle

    const int tid  = threadIdx.x;
    const int lane = tid & 63;
    const int w    = tid >> 6;
    const int wm = w >> 1, wn = w & 1;
    // XCD swizzle: 6144 blocks = 8 XCD * 768 slots; same-ntile's 12 mblk blocks
    // are consecutive slots on ONE XCD (assumes round-robin blockIdx->XCD).
    const int xcd  = blockIdx.x & 7;
    const int slot = blockIdx.x >> 3;          // 0..767
    const int ntile = xcd + 8 * (slot / 12);   // 0..511
    const int mblk  = slot % 12;
    const int bb = ntile >> 4;
    const int l0 = (ntile & 15) << 7;
    const int lane15 = lane & 15, kgrp = lane >> 4;

    // B-staging assignment: thread -> (row n, half-row hr)
    const int nrow = tid >> 1;
    const int hr   = tid & 1;

    f32x4 acc[4][4];
#pragma unroll
    for (int a = 0; a < 4; ++a)
#pragma unroll
        for (int c = 0; c < 4; ++c) acc[a][c] = (f32x4){0.f, 0.f, 0.f, 0.f};

    for (int iter = 0; iter < 24; ++iter) {
        const int kk   = iter >> 3;
        const int iblk = iter & 7;
        // ---- stage A (weights, fp16): contiguous 16 KB block, async DMA ----
        const char* srcA =
            (const char*)(Wrp + (((size_t)(mblk * 3 + kk) * 8 + iblk) << 13));
#pragma unroll
        for (int s = 0; s < 4; ++s) {
            int base = s * 4096 + w * 1024;            // wave-uniform LDS base
            __builtin_amdgcn_global_load_lds(
                (const __attribute__((address_space(1))) unsigned int*)(srcA + base + lane * 16),
                (__attribute__((address_space(3))) unsigned int*)((char*)lA + base),
                16, 0, 0);
        }
        // ---- stage B (activations): fp32 loads -> fp16 -> swizzled LDS ----
        const int i0 = iblk << 6;
        const int l  = l0 + nrow + kk - 1;
        if (l >= 0 && l < L_) {
            const f32x4* gp =
                (const f32x4*)(t + (((size_t)bb * L_ + l) * U_ + i0 + hr * 32));
            f32x4 gr[8];
#pragma unroll
            for (int j = 0; j < 8; ++j) gr[j] = gp[j];
#pragma unroll
            for (int j = 0; j < 4; ++j) {
                auto p0 = __builtin_amdgcn_cvt_pkrtz(gr[2 * j][0], gr[2 * j][1]);
                auto p1 = __builtin_amdgcn_cvt_pkrtz(gr[2 * j][2], gr[2 * j][3]);
                auto p2 = __builtin_amdgcn_cvt_pkrtz(gr[2 * j + 1][0], gr[2 * j + 1][1]);
                auto p3 = __builtin_amdgcn_cvt_pkrtz(gr[2 * j + 1][2], gr[2 * j + 1][3]);
                half8 hv;
                hv[0] = p0[0]; hv[1] = p0[1]; hv[2] = p1[0]; hv[3] = p1[1];
                hv[4] = p2[0]; hv[5] = p2[1]; hv[6] = p3[0]; hv[7] = p3[1];
                const int c = hr * 4 + j;              // logical 16B chunk
                *(half8*)((char*)lB + nrow * 128 + (((c ^ (nrow & 7))) << 4)) = hv;
            }
        } else {                                       // conv zero padding row
            half8 z = {};
#pragma unroll
            for (int j = 0; j < 4; ++j) {
                const int c = hr * 4 + j;
                *(half8*)((char*)lB + nrow * 128 + (((c ^ (nrow & 7))) << 4)) = z;
            }
        }
        __syncthreads();
        // ---- compute: 32 MFMA ----
        half8 af[2][4], bfr[2][4];
#pragma unroll
        for (int ks = 0; ks < 2; ++ks) {
            const int c = ks * 4 + kgrp;               // logical 16B chunk
#pragma unroll
            for (int mi = 0; mi < 4; ++mi) {
                int r = wm * 64 + mi * 16 + lane15;
                af[ks][mi] = *(const half8*)((const char*)lA + r * 128 +
                                             ((c ^ (r & 7)) << 4));
            }
#pragma unroll
            for (int ni = 0; ni < 4; ++ni) {
                int n = wn * 64 + ni * 16 + lane15;
                bfr[ks][ni] = *(const half8*)((const char*)lB + n * 128 +
                                              ((c ^ (n & 7)) << 4));
            }
        }
#pragma unroll
        for (int ks = 0; ks < 2; ++ks)
#pragma unroll
            for (int mi = 0; mi < 4; ++mi)
#pragma unroll
                for (int ni = 0; ni < 4; ++ni)
                    acc[mi][ni] = __builtin_amdgcn_mfma_f32_16x16x32_f16(
                        af[ks][mi], bfr[ks][ni], acc[mi][ni], 0, 0, 0);
        __syncthreads();
    }

    // ---- epilogue ----
    const int mat = mblk >> 2;                         // 0=q 1=k 2=v
    const float* bias = (mat == 0) ? bq : (mat == 1) ? bk : bv;
    const int oBase = ((mblk & 3) << 7) + wm * 64 + kgrp * 4;
#pragma unroll
    for (int mi = 0; mi < 4; ++mi) {
#pragma unroll
        for (int r = 0; r < 4; ++r) {
            const int o = oBase + mi * 16 + r;         // channel within matrix
            const float bsv = bias[o];
            float vals[4];
            float mx = -3.0e38f;
#pragma unroll
            for (int ni = 0; ni < 4; ++ni) {
                float v = acc[mi][ni][r] + bsv;
                vals[ni] = v;
                mx = fmaxf(mx, v);
            }
#pragma unroll
            for (int d = 1; d < 16; d <<= 1) mx = fmaxf(mx, __shfl_xor(mx, d, 64));
            if (mat == 0) {
                if (lane15 == 0) atomicMax(&qmaxU[bb * U_ + o], fmap(mx));
            } else {
                __half* buf = (mat == 1) ? kbuf : vbuf;
                size_t rowbase = ((size_t)bb * U_ + o) * L_ + l0 + wn * 64;
#pragma unroll
                for (int ni = 0; ni < 4; ++ni)
                    buf[rowbase + ni * 16 + lane15] = __float2half(vals[ni]);
                unsigned* mptr = (mat == 1) ? kmaxU : vmaxU;
                if (lane15 == 0) atomicMax(&mptr[bb * U_ + o], fmap(mx));
            }
        }
    }
}

// ---------------------------------------------------------------------------
// Kernel 3: per-(b,h) attention: on-the-fly maxpool3 of k,v + masked softmax
// over 2049 keys (global key from kmax/vmax), output (B,H,HD) fp32.
// ---------------------------------------------------------------------------
__global__ void __launch_bounds__(256) attn_kernel(
    const __half* __restrict__ kbuf, const __half* __restrict__ vbuf,
    const unsigned* __restrict__ qmaxU, const unsigned* __restrict__ kmaxU,
    const unsigned* __restrict__ vmaxU,
    const int* __restrict__ g_mask, const int* __restrict__ t_mask,
    float* __restrict__ attout) {
    const int bh = blockIdx.x;
    const int b = bh >> 3, h = bh & 7;
    const int tid = threadIdx.x;
    __shared__ float qs[64], kg[64], vg[64];
    __shared__ float pl[2048];
    __shared__ float red[256];
    if (tid < 64) {
        qs[tid] = funmap(qmaxU[b * U_ + h * 64 + tid]);
        kg[tid] = funmap(kmaxU[b * U_ + h * 64 + tid]);
        vg[tid] = funmap(vmaxU[b * U_ + h * 64 + tid]);
    }
    __syncthreads();
    const float scale = 0.044194173824159216f;   // 1/sqrt(512)

    // logits for the 2048 local (pooled) keys; thread owns 8 positions
    const __half* kbase = kbuf + ((size_t)b * U_ + h * 64) * L_;
    const int l0 = tid * 8;
    float acc[8];
#pragma unroll
    for (int j = 0; j < 8; ++j) acc[j] = 0.f;
    for (int o = 0; o < 64; ++o) {
        const __half* row = kbase + (size_t)o * L_;
        union { uint4 u; __half hh[8]; } pk;
        pk.u = *(const uint4*)(row + l0);
        float f[10];
#pragma unroll
        for (int j = 0; j < 8; ++j) f[j + 1] = __half2float(pk.hh[j]);
        f[0] = (l0 == 0) ? -3.0e38f : __half2float(row[l0 - 1]);
        f[9] = (l0 + 8 >= L_) ? -3.0e38f : __half2float(row[l0 + 8]);
        const float qw = qs[o];
#pragma unroll
        for (int j = 0; j < 8; ++j)
            acc[j] += qw * fmaxf(f[j], fmaxf(f[j + 1], f[j + 2]));
    }
    float lmax = -3.0e38f;
#pragma unroll
    for (int j = 0; j < 8; ++j) {
        int tm = t_mask[b * L_ + l0 + j];
        float lg = (tm == 0) ? -INFINITY : acc[j] * scale;
        pl[l0 + j] = lg;
        lmax = fmaxf(lmax, lg);
    }
    // global-key logit (redundantly on all threads; cheap)
    float ag = 0.f;
    for (int d = 0; d < 64; ++d) ag += qs[d] * kg[d];
    const int gm = g_mask[b];
    float lgg = gm ? ag * scale : -INFINITY;
    // block max
    red[tid] = lmax; __syncthreads();
    for (int s = 128; s > 0; s >>= 1) {
        if (tid < s) red[tid] = fmaxf(red[tid], red[tid + s]);
        __syncthreads();
    }
    float mx = fmaxf(red[0], lgg);
    __syncthreads();
    // exponentials + denominator
    float lsum = 0.f;
#pragma unroll
    for (int j = 0; j < 8; ++j) {
        float lg = pl[l0 + j];
        float e = (lg <= -3.0e38f) ? 0.f : __expf(lg - mx);
        pl[l0 + j] = e;
        lsum += e;
    }
    red[tid] = lsum; __syncthreads();
    for (int s = 128; s > 0; s >>= 1) {
        if (tid < s) red[tid] += red[tid + s];
        __syncthreads();
    }
    float eg = gm ? __expf(lgg - mx) : 0.f;
    float den = red[0] + eg;
    if (!(den > 0.f)) den = 1.f;
    __syncthreads();
    // weighted sum of pooled values: thread = (o = tid/4, chunk = tid%4 of 512 l's)
    const int o = tid >> 2;
    const int ch = tid & 3;
    const __half* vrow = vbuf + ((size_t)b * U_ + h * 64 + o) * L_;
    float s = 0.f;
    for (int lb = ch * 512; lb < ch * 512 + 512; lb += 8) {
        union { uint4 u; __half hh[8]; } pk;
        pk.u = *(const uint4*)(vrow + lb);
        float f[10];
#pragma unroll
        for (int j = 0; j < 8; ++j) f[j + 1] = __half2float(pk.hh[j]);
        f[0] = (lb == 0) ? -3.0e38f : __half2float(vrow[lb - 1]);
        f[9] = (lb + 8 >= L_) ? -3.0e38f : __half2float(vrow[lb + 8]);
#pragma unroll
        for (int j = 0; j < 8; ++j)
            s += pl[lb + j] * fmaxf(f[j], fmaxf(f[j + 1], f[j + 2]));
    }
    red[tid] = s; __syncthreads();
    if (ch == 0) {
        float tot = red[tid] + red[tid + 1] + red[tid + 2] + red[tid + 3];
        float val = (eg * vg[o] + tot) / den;
        val *= (float)gm;
        attout[(size_t)b * U_ + h * 64 + o] = val;
    }
}

// ---------------------------------------------------------------------------
// Kernel 4: head mix (H x H) + output projection (U x U), out fp32 (B,1,U)
// ---------------------------------------------------------------------------
__global__ void __launch_bounds__(512) out_kernel(
    const float* __restrict__ attout,
    const float* __restrict__ Wh, const float* __restrict__ bh,
    const float* __restrict__ Wo, const float* __restrict__ bo,
    float* __restrict__ out) {
    const int b = blockIdx.x;
    const int tid = threadIdx.x;
    __shared__ float tmp[512];
    const int oh = tid >> 6, d = tid & 63;
    float s = bh[oh];
#pragma unroll
    for (int i = 0; i < 8; ++i)
        s += Wh[oh * 8 + i] * attout[b * U_ + i * 64 + d];
    tmp[oh * 64 + d] = s;          // u = h*64 + d
    __syncthreads();
    float s2 = bo[tid];
    const float* wrow = Wo + tid * 512;
    for (int i = 0; i < 512; ++i) s2 += wrow[i] * tmp[i];
    out[b * U_ + tid] = s2;
}

// ---------------------------------------------------------------------------
extern "C" void kernel_launch(void* const* d_in, const int* in_sizes, int n_in,
                              void* d_out, int out_size, void* d_ws, size_t ws_size,
                              hipStream_t stream) {
    const float* t  = (const float*)d_in[0];
    // d_in[1] = g : unused by the reference
    const int* g_mask = (const int*)d_in[2];
    const int* t_mask = (const int*)d_in[3];
    const float* Wq = (const float*)d_in[4];
    const float* bq = (const float*)d_in[5];
    const float* Wk = (const float*)d_in[6];
    const float* bk = (const float*)d_in[7];
    const float* Wv = (const float*)d_in[8];
    const float* bv = (const float*)d_in[9];
    const float* Wh = (const float*)d_in[10];
    const float* bh = (const float*)d_in[11];
    const float* Wo = (const float*)d_in[12];
    const float* bo = (const float*)d_in[13];

    char* ws = (char*)d_ws;
    __half* Wrp = (__half*)ws;                                       // 4,718,592 B
    __half* kbuf = (__half*)(ws + 4718592);                          // 67,108,864 B
    __half* vbuf = (__half*)(ws + 4718592 + 67108864);               // 67,108,864 B
    unsigned* qmaxU = (unsigned*)(ws + 4718592 + 2 * 67108864);      // 64 KB
    unsigned* kmaxU = qmaxU + 16384;
    unsigned* vmaxU = kmaxU + 16384;
    float* attout = (float*)(vmaxU + 16384);                         // 64 KB

    (void)hipMemsetAsync(qmaxU, 0, 3 * 16384 * sizeof(unsigned), stream);
    repack_w<<<9216, 256, 0, stream>>>(Wq, Wk, Wv, Wrp);
    conv_gemm<<<6144, 256, 0, stream>>>(t, Wrp, bq, bk, bv, kbuf, vbuf,
                                        qmaxU, kmaxU, vmaxU);
    attn_kernel<<<256, 256, 0, stream>>>(kbuf, vbuf, qmaxU, kmaxU, vmaxU,
                                         g_mask, t_mask, attout);
    out_kernel<<<32, 512, 0, stream>>>(attout, Wh, bh, Wo, bo, (float*)d_out);
}

// Round 5
// 781.729 us; speedup vs baseline: 1.2998x; 1.2876x over previous
//
#include <hip/hip_runtime.h>
#include <hip/hip_fp16.h>

#define B_  32
#define L_  2048
#define U_  512
#define H_  8
#define HD_ 64

typedef __attribute__((ext_vector_type(8))) _Float16 half8;
typedef __attribute__((ext_vector_type(4))) float f32x4;

// monotonic float->uint map for atomic max (works for negatives)
__device__ __forceinline__ unsigned fmap(float x) {
    unsigned u = __float_as_uint(x);
    return (u & 0x80000000u) ? ~u : (u | 0x80000000u);
}
__device__ __forceinline__ float funmap(unsigned m) {
    unsigned bits = (m & 0x80000000u) ? (m ^ 0x80000000u) : ~m;
    return __uint_as_float(bits);
}

// ---------------------------------------------------------------------------
// Kernel 1: repack [Wq;Wk;Wv] (O,I,3) fp32 -> fp16 tile-blocked, chunk-swizzled.
// Layout: Wrp[mblk][kk][iblk][m(128)][chunk(8)][e(8)] fp16; stored 16B chunk
// c_st holds logical chunk c_st ^ (m&7)  (LDS bank swizzle).
// ---------------------------------------------------------------------------
__global__ void repack_w(const float* __restrict__ Wq,
                         const float* __restrict__ Wk,
                         const float* __restrict__ Wv,
                         __half* __restrict__ Wrp) {
    int id = blockIdx.x * 256 + threadIdx.x;       // 2,359,296 total
    int e    = id & 7;
    int c_st = (id >> 3) & 7;
    int m    = (id >> 6) & 127;
    int blk  = id >> 13;                           // (mblk*3+kk)*8+iblk
    int iblk = blk & 7;
    int kk   = (blk >> 3) % 3;
    int mblk = blk / 24;
    int o = mblk * 128 + m;
    const float* W = (o < 512) ? Wq : (o < 1024) ? Wk : Wv;
    int ol = o & 511;
    int ig = iblk * 64 + ((c_st ^ (m & 7)) << 3) + e;
    Wrp[id] = __float2half(W[(ol * 512 + ig) * 3 + kk]);
}

// ---------------------------------------------------------------------------
// Kernel 2: fused conv1d(K=3) GEMM, tap-fused B-staging.
//  C[o,(b,l)] = sum_{i,kk} W[o,i,kk] * t[b, l+kk-1, i]
//  Per iblk: stage 130-row B-tile ONCE (rows l0-1..l0+128) + A for all 3 taps,
//  then 3 taps x 32 MFMA = 96 MFMA per barrier-pair (tap = +kk row offset in LDS).
//  Barriers per block: 16 (was 48). LDS 65 KB -> 2 blocks/CU.
// ---------------------------------------------------------------------------
__global__ void __launch_bounds__(256) conv_gemm(
    const float* __restrict__ t,      // fp32 (B,L,U)
    const __half* __restrict__ Wrp,
    const float* __restrict__ bq,
    const float* __restrict__ bk,
    const float* __restrict__ bv,
    __half* __restrict__ kbuf, __half* __restrict__ vbuf,
    unsigned* __restrict__ qmaxU, unsigned* __restrict__ kmaxU,
    unsigned* __restrict__ vmaxU) {
    __shared__ _Float16 lA[3][128 * 64];   // 48 KB: per-tap A, 16B-chunk swizzle
    __shared__ _Float16 lB[130 * 64];      // 16.6 KB: rows l0-1..l0+128

    const int tid  = threadIdx.x;
    const int lane = tid & 63;
    const int w    = tid >> 6;
    const int wm = w >> 1, wn = w & 1;
    // XCD swizzle: same-ntile's 12 mblk blocks land consecutively on ONE XCD.
    const int xcd  = blockIdx.x & 7;
    const int slot = blockIdx.x >> 3;          // 0..767
    const int ntile = xcd + 8 * (slot / 12);   // 0..511
    const int mblk  = slot % 12;
    const int bb = ntile >> 4;
    const int l0 = (ntile & 15) << 7;
    const int lane15 = lane & 15, kgrp = lane >> 4;

    const int nrow = tid >> 1;                 // B-staging: row 0..127
    const int hr   = tid & 1;                  // half-row (32 floats)

    f32x4 acc[4][4];
#pragma unroll
    for (int a = 0; a < 4; ++a)
#pragma unroll
        for (int c = 0; c < 4; ++c) acc[a][c] = (f32x4){0.f, 0.f, 0.f, 0.f};

    for (int iblk = 0; iblk < 8; ++iblk) {
        const int i0 = iblk << 6;
        // ---- stage A: 3 taps x 16 KB async DMA ----
#pragma unroll
        for (int kk = 0; kk < 3; ++kk) {
            const char* srcA =
                (const char*)(Wrp + (((size_t)(mblk * 3 + kk) * 8 + iblk) << 13));
#pragma unroll
            for (int s = 0; s < 4; ++s) {
                int base = s * 4096 + w * 1024;        // wave-uniform LDS base
                __builtin_amdgcn_global_load_lds(
                    (const __attribute__((address_space(1))) unsigned int*)(srcA + base + lane * 16),
                    (__attribute__((address_space(3))) unsigned int*)((char*)lA[kk] + base),
                    16, 0, 0);
            }
        }
        // ---- stage B: 130 rows, fp32 global -> cvt -> fp16 swizzled LDS ----
#pragma unroll
        for (int rep = 0; rep < 2; ++rep) {
            int rbuf = (rep == 0) ? nrow : 128 + nrow;
            if (rbuf < 130) {
                const int l = l0 - 1 + rbuf;
                if (l >= 0 && l < L_) {
                    const f32x4* gp =
                        (const f32x4*)(t + (((size_t)bb * L_ + l) * U_ + i0 + hr * 32));
                    f32x4 gr[8];
#pragma unroll
                    for (int j = 0; j < 8; ++j) gr[j] = gp[j];
#pragma unroll
                    for (int j = 0; j < 4; ++j) {
                        auto p0 = __builtin_amdgcn_cvt_pkrtz(gr[2 * j][0], gr[2 * j][1]);
                        auto p1 = __builtin_amdgcn_cvt_pkrtz(gr[2 * j][2], gr[2 * j][3]);
                        auto p2 = __builtin_amdgcn_cvt_pkrtz(gr[2 * j + 1][0], gr[2 * j + 1][1]);
                        auto p3 = __builtin_amdgcn_cvt_pkrtz(gr[2 * j + 1][2], gr[2 * j + 1][3]);
                        half8 hv;
                        hv[0] = p0[0]; hv[1] = p0[1]; hv[2] = p1[0]; hv[3] = p1[1];
                        hv[4] = p2[0]; hv[5] = p2[1]; hv[6] = p3[0]; hv[7] = p3[1];
                        const int c = hr * 4 + j;      // logical 16B chunk
                        *(half8*)((char*)lB + rbuf * 128 + ((c ^ (rbuf & 7)) << 4)) = hv;
                    }
                } else {                               // conv zero padding row
                    half8 z = {};
#pragma unroll
                    for (int j = 0; j < 4; ++j) {
                        const int c = hr * 4 + j;
                        *(half8*)((char*)lB + rbuf * 128 + ((c ^ (rbuf & 7)) << 4)) = z;
                    }
                }
            }
        }
        __syncthreads();
        // ---- compute: 3 taps x 32 MFMA (tap = row offset kk in lB) ----
#pragma unroll
        for (int kk = 0; kk < 3; ++kk) {
            half8 af[2][4], bfr[2][4];
#pragma unroll
            for (int ks = 0; ks < 2; ++ks) {
                const int c = ks * 4 + kgrp;           // logical 16B chunk
#pragma unroll
                for (int mi = 0; mi < 4; ++mi) {
                    int r = wm * 64 + mi * 16 + lane15;
                    af[ks][mi] = *(const half8*)((const char*)lA[kk] + r * 128 +
                                                 ((c ^ (r & 7)) << 4));
                }
#pragma unroll
                for (int ni = 0; ni < 4; ++ni) {
                    int rbuf = wn * 64 + ni * 16 + lane15 + kk;
                    bfr[ks][ni] = *(const half8*)((const char*)lB + rbuf * 128 +
                                                  ((c ^ (rbuf & 7)) << 4));
                }
            }
#pragma unroll
            for (int ks = 0; ks < 2; ++ks)
#pragma unroll
                for (int mi = 0; mi < 4; ++mi)
#pragma unroll
                    for (int ni = 0; ni < 4; ++ni)
                        acc[mi][ni] = __builtin_amdgcn_mfma_f32_16x16x32_f16(
                            af[ks][mi], bfr[ks][ni], acc[mi][ni], 0, 0, 0);
        }
        __syncthreads();
    }

    // ---- epilogue ----
    const int mat = mblk >> 2;                         // 0=q 1=k 2=v
    const float* bias = (mat == 0) ? bq : (mat == 1) ? bk : bv;
    const int oBase = ((mblk & 3) << 7) + wm * 64 + kgrp * 4;
#pragma unroll
    for (int mi = 0; mi < 4; ++mi) {
#pragma unroll
        for (int r = 0; r < 4; ++r) {
            const int o = oBase + mi * 16 + r;         // channel within matrix
            const float bsv = bias[o];
            float vals[4];
            float mx = -3.0e38f;
#pragma unroll
            for (int ni = 0; ni < 4; ++ni) {
                float v = acc[mi][ni][r] + bsv;
                vals[ni] = v;
                mx = fmaxf(mx, v);
            }
#pragma unroll
            for (int d = 1; d < 16; d <<= 1) mx = fmaxf(mx, __shfl_xor(mx, d, 64));
            if (mat == 0) {
                if (lane15 == 0) atomicMax(&qmaxU[bb * U_ + o], fmap(mx));
            } else {
                __half* buf = (mat == 1) ? kbuf : vbuf;
                size_t rowbase = ((size_t)bb * U_ + o) * L_ + l0 + wn * 64;
#pragma unroll
                for (int ni = 0; ni < 4; ++ni)
                    buf[rowbase + ni * 16 + lane15] = __float2half(vals[ni]);
                unsigned* mptr = (mat == 1) ? kmaxU : vmaxU;
                if (lane15 == 0) atomicMax(&mptr[bb * U_ + o], fmap(mx));
            }
        }
    }
}

// ---------------------------------------------------------------------------
// Kernel 3: per-(b,h) attention, 1024 threads (16 waves) for latency hiding.
// On-the-fly maxpool3 of k,v + masked softmax over 2049 keys.
// ---------------------------------------------------------------------------
__global__ void __launch_bounds__(1024) attn_kernel(
    const __half* __restrict__ kbuf, const __half* __restrict__ vbuf,
    const unsigned* __restrict__ qmaxU, const unsigned* __restrict__ kmaxU,
    const unsigned* __restrict__ vmaxU,
    const int* __restrict__ g_mask, const int* __restrict__ t_mask,
    float* __restrict__ attout) {
    const int bh = blockIdx.x;
    const int b = bh >> 3, h = bh & 7;
    const int tid = threadIdx.x;
    __shared__ float qs[64], kg[64], vg[64];
    __shared__ float pl[2048];
    __shared__ float red[1024];
    if (tid < 64) {
        qs[tid] = funmap(qmaxU[b * U_ + h * 64 + tid]);
        kg[tid] = funmap(kmaxU[b * U_ + h * 64 + tid]);
        vg[tid] = funmap(vmaxU[b * U_ + h * 64 + tid]);
    }
    __syncthreads();
    const float scale = 0.044194173824159216f;   // 1/sqrt(512)

    // logits for 2048 local (pooled) keys; thread owns 2 positions
    const __half* kbase = kbuf + ((size_t)b * U_ + h * 64) * L_;
    const int l0 = tid * 2;
    float acc0 = 0.f, acc1 = 0.f;
    for (int o = 0; o < 64; ++o) {
        const __half* row = kbase + (size_t)o * L_;
        float f0 = (l0 == 0) ? -3.0e38f : __half2float(row[l0 - 1]);
        float f1 = __half2float(row[l0]);
        float f2 = __half2float(row[l0 + 1]);
        float f3 = (l0 + 2 >= L_) ? -3.0e38f : __half2float(row[l0 + 2]);
        const float qw = qs[o];
        acc0 += qw * fmaxf(f0, fmaxf(f1, f2));
        acc1 += qw * fmaxf(f1, fmaxf(f2, f3));
    }
    float lmax = -3.0e38f;
    {
        int tm0 = t_mask[b * L_ + l0], tm1 = t_mask[b * L_ + l0 + 1];
        float lg0 = (tm0 == 0) ? -INFINITY : acc0 * scale;
        float lg1 = (tm1 == 0) ? -INFINITY : acc1 * scale;
        pl[l0] = lg0; pl[l0 + 1] = lg1;
        lmax = fmaxf(lg0, lg1);
    }
    // global-key logit (redundantly on all threads; cheap)
    float ag = 0.f;
    for (int d = 0; d < 64; ++d) ag += qs[d] * kg[d];
    const int gm = g_mask[b];
    float lgg = gm ? ag * scale : -INFINITY;
    // block max
    red[tid] = lmax; __syncthreads();
    for (int s = 512; s > 0; s >>= 1) {
        if (tid < s) red[tid] = fmaxf(red[tid], red[tid + s]);
        __syncthreads();
    }
    float mx = fmaxf(red[0], lgg);
    __syncthreads();
    // exponentials + denominator
    {
        float lg0 = pl[l0], lg1 = pl[l0 + 1];
        float e0 = (lg0 <= -3.0e38f) ? 0.f : __expf(lg0 - mx);
        float e1 = (lg1 <= -3.0e38f) ? 0.f : __expf(lg1 - mx);
        pl[l0] = e0; pl[l0 + 1] = e1;
        red[tid] = e0 + e1;
    }
    __syncthreads();
    for (int s = 512; s > 0; s >>= 1) {
        if (tid < s) red[tid] += red[tid + s];
        __syncthreads();
    }
    float eg = gm ? __expf(lgg - mx) : 0.f;
    float den = red[0] + eg;
    if (!(den > 0.f)) den = 1.f;
    __syncthreads();
    // weighted sum of pooled values: thread = (o = tid/16, 16 chunks of 128 l's)
    const int o = tid >> 4;
    const int ch = tid & 15;
    const __half* vrow = vbuf + ((size_t)b * U_ + h * 64 + o) * L_;
    float s = 0.f;
    for (int lb = ch * 128; lb < ch * 128 + 128; lb += 8) {
        union { uint4 u; __half hh[8]; } pk;
        pk.u = *(const uint4*)(vrow + lb);
        float f[10];
#pragma unroll
        for (int j = 0; j < 8; ++j) f[j + 1] = __half2float(pk.hh[j]);
        f[0] = (lb == 0) ? -3.0e38f : __half2float(vrow[lb - 1]);
        f[9] = (lb + 8 >= L_) ? -3.0e38f : __half2float(vrow[lb + 8]);
#pragma unroll
        for (int j = 0; j < 8; ++j)
            s += pl[lb + j] * fmaxf(f[j], fmaxf(f[j + 1], f[j + 2]));
    }
    red[tid] = s; __syncthreads();
    if (ch == 0) {
        float tot = 0.f;
#pragma unroll
        for (int q2 = 0; q2 < 16; ++q2) tot += red[(o << 4) + q2];
        float val = (eg * vg[o] + tot) / den;
        val *= (float)gm;
        attout[(size_t)b * U_ + h * 64 + o] = val;
    }
}

// ---------------------------------------------------------------------------
// Kernel 4: head mix (H x H) + output projection (U x U), out fp32 (B,1,U)
// ---------------------------------------------------------------------------
__global__ void __launch_bounds__(512) out_kernel(
    const float* __restrict__ attout,
    const float* __restrict__ Wh, const float* __restrict__ bh,
    const float* __restrict__ Wo, const float* __restrict__ bo,
    float* __restrict__ out) {
    const int b = blockIdx.x;
    const int tid = threadIdx.x;
    __shared__ float tmp[512];
    const int oh = tid >> 6, d = tid & 63;
    float s = bh[oh];
#pragma unroll
    for (int i = 0; i < 8; ++i)
        s += Wh[oh * 8 + i] * attout[b * U_ + i * 64 + d];
    tmp[oh * 64 + d] = s;          // u = h*64 + d
    __syncthreads();
    float s2 = bo[tid];
    const float* wrow = Wo + tid * 512;
    for (int i = 0; i < 512; ++i) s2 += wrow[i] * tmp[i];
    out[b * U_ + tid] = s2;
}

// ---------------------------------------------------------------------------
extern "C" void kernel_launch(void* const* d_in, const int* in_sizes, int n_in,
                              void* d_out, int out_size, void* d_ws, size_t ws_size,
                              hipStream_t stream) {
    const float* t  = (const float*)d_in[0];
    // d_in[1] = g : unused by the reference
    const int* g_mask = (const int*)d_in[2];
    const int* t_mask = (const int*)d_in[3];
    const float* Wq = (const float*)d_in[4];
    const float* bq = (const float*)d_in[5];
    const float* Wk = (const float*)d_in[6];
    const float* bk = (const float*)d_in[7];
    const float* Wv = (const float*)d_in[8];
    const float* bv = (const float*)d_in[9];
    const float* Wh = (const float*)d_in[10];
    const float* bh = (const float*)d_in[11];
    const float* Wo = (const float*)d_in[12];
    const float* bo = (const float*)d_in[13];

    char* ws = (char*)d_ws;
    __half* Wrp = (__half*)ws;                                       // 4,718,592 B
    __half* kbuf = (__half*)(ws + 4718592);                          // 67,108,864 B
    __half* vbuf = (__half*)(ws + 4718592 + 67108864);               // 67,108,864 B
    unsigned* qmaxU = (unsigned*)(ws + 4718592 + 2 * 67108864);      // 64 KB
    unsigned* kmaxU = qmaxU + 16384;
    unsigned* vmaxU = kmaxU + 16384;
    float* attout = (float*)(vmaxU + 16384);                         // 64 KB

    (void)hipMemsetAsync(qmaxU, 0, 3 * 16384 * sizeof(unsigned), stream);
    repack_w<<<9216, 256, 0, stream>>>(Wq, Wk, Wv, Wrp);
    conv_gemm<<<6144, 256, 0, stream>>>(t, Wrp, bq, bk, bv, kbuf, vbuf,
                                        qmaxU, kmaxU, vmaxU);
    attn_kernel<<<256, 1024, 0, stream>>>(kbuf, vbuf, qmaxU, kmaxU, vmaxU,
                                          g_mask, t_mask, attout);
    out_kernel<<<32, 512, 0, stream>>>(attout, Wh, bh, Wo, bo, (float*)d_out);
}

// Round 6
// 757.535 us; speedup vs baseline: 1.3413x; 1.0319x over previous
//
#include <hip/hip_runtime.h>
#include <hip/hip_fp16.h>

#define B_  32
#define L_  2048
#define U_  512
#define H_  8
#define HD_ 64

typedef __attribute__((ext_vector_type(8))) _Float16 half8;
typedef __attribute__((ext_vector_type(4))) float f32x4;

// monotonic float->uint map for atomic max (works for negatives)
__device__ __forceinline__ unsigned fmap(float x) {
    unsigned u = __float_as_uint(x);
    return (u & 0x80000000u) ? ~u : (u | 0x80000000u);
}
__device__ __forceinline__ float funmap(unsigned m) {
    unsigned bits = (m & 0x80000000u) ? (m ^ 0x80000000u) : ~m;
    return __uint_as_float(bits);
}

// ---------------------------------------------------------------------------
// Kernel 1a: repack [Wq;Wk;Wv] (O,I,3) fp32 -> fp16 in DIRECT A-FRAGMENT order:
// Wrp2[(mblk*2+wm)][frag F][lane][8], F = ((iblk*3+kk)*2+ks)*4+mi.
// A wave loads frag F with one global_load_dwordx4 at base + F*1024 + lane*16.
// ---------------------------------------------------------------------------
__global__ void repack_w2(const float* __restrict__ Wq,
                          const float* __restrict__ Wk,
                          const float* __restrict__ Wv,
                          __half* __restrict__ Wrp2) {
    int id = blockIdx.x * 256 + threadIdx.x;       // 294,912 units of 8 halves
    int mb2  = id / 12288;                         // mblk*2+wm  (0..23)
    int rem  = id % 12288;
    int F    = rem >> 6;                           // 0..191
    int lane = rem & 63;
    int mblk = mb2 >> 1, wm = mb2 & 1;
    int mi = F & 3, ks = (F >> 2) & 1, t3 = F >> 3;
    int kk = t3 % 3, iblk = t3 / 3;
    int mat = mblk >> 2;
    const float* W = (mat == 0) ? Wq : (mat == 1) ? Wk : Wv;
    int ol = ((mblk & 3) << 7) + wm * 64 + mi * 16 + (lane & 15);  // A row (m)
    int ib = iblk * 64 + ks * 32 + (lane >> 4) * 8;                // A col (k)
    half8 hv;
#pragma unroll
    for (int j = 0; j < 8; ++j)
        hv[j] = (_Float16)W[(ol * 512 + ib + j) * 3 + kk];
    *(half8*)(Wrp2 + (size_t)id * 8) = hv;
}

// Kernel 1b: transpose Wo (O,I) -> WoT (I,O) for coalesced out_kernel reads
__global__ void wot_repack(const float* __restrict__ Wo, float* __restrict__ WoT) {
    int id = blockIdx.x * 256 + threadIdx.x;       // 262,144
    int o = id & 511, i = id >> 9;
    WoT[(size_t)i * 512 + o] = Wo[(size_t)o * 512 + i];
}

// ---------------------------------------------------------------------------
// Kernel 2: fused conv1d(K=3) GEMM, restructured K-loop:
//  - A fragments: direct global->VGPR loads (L2-resident, no LDS round trip)
//  - B tile (130 rows x 64 ch fp32): async global_load_lds DMA, double-buffered,
//    prefetched one iblk ahead; swizzle baked into SOURCE addresses (16B pieces,
//    key = l&15 -> 2-way bank aliasing = free).
//  - ONE barrier per iteration (8 total). fp32->fp16 cvt at fragment read.
// ---------------------------------------------------------------------------
__global__ void __launch_bounds__(256, 2) conv_gemm(
    const float* __restrict__ t,      // fp32 (B,L,U)
    const __half* __restrict__ Wrp2,
    const float* __restrict__ bq,
    const float* __restrict__ bk,
    const float* __restrict__ bv,
    __half* __restrict__ kbuf, __half* __restrict__ vbuf,
    unsigned* __restrict__ qmaxU, unsigned* __restrict__ kmaxU,
    unsigned* __restrict__ vmaxU) {
    __shared__ float lB[2][130 * 64];   // 66.6 KB total: rows l0-1..l0+128, fp32

    const int tid  = threadIdx.x;
    const int lane = tid & 63;
    const int w    = tid >> 6;
    const int wm = w >> 1, wn = w & 1;
    // XCD swizzle: same-ntile's 12 mblk blocks land consecutively on ONE XCD.
    const int xcd  = blockIdx.x & 7;
    const int slot = blockIdx.x >> 3;          // 0..767
    const int ntile = xcd + 8 * (slot / 12);   // 0..511
    const int mblk  = slot % 12;
    const int bb = ntile >> 4;
    const int l0 = (ntile & 15) << 7;
    const int lane15 = lane & 15, kgrp = lane >> 4;

    const char* Abase = (const char*)Wrp2 + (size_t)(mblk * 2 + wm) * 196608;
    const char* tB = (const char*)(t + (size_t)bb * L_ * U_);

    f32x4 acc[4][4];
#pragma unroll
    for (int a = 0; a < 4; ++a)
#pragma unroll
        for (int c = 0; c < 4; ++c) acc[a][c] = (f32x4){0.f, 0.f, 0.f, 0.f};

    // ---- B-stage: async DMA of 130 rows x 256B, swizzled source ----
    auto stageB = [&](int nb, int buf) {
        const int i0 = nb << 6;
#pragma unroll
        for (int d = 0; d < 8; ++d) {
            const int rowb = w * 32 + d * 4;               // wave-uniform
            const int row  = rowb + (lane >> 4);
            const int l    = l0 - 1 + row;
            const int p16  = lane & 15;
            const char* g = tB + ((size_t)l * U_ + i0) * 4 + ((p16 ^ (l & 15)) << 4);
            if (l >= 0 && l < L_)
                __builtin_amdgcn_global_load_lds(
                    (const __attribute__((address_space(1))) unsigned int*)g,
                    (__attribute__((address_space(3))) unsigned int*)((char*)lB[buf] + rowb * 256),
                    16, 0, 0);
        }
        if (w == 0 && lane < 32) {                         // rows 128,129
            const int row = 128 + (lane >> 4);
            const int l   = l0 - 1 + row;
            const int p16 = lane & 15;
            const char* g = tB + ((size_t)l * U_ + i0) * 4 + ((p16 ^ (l & 15)) << 4);
            if (l >= 0 && l < L_)
                __builtin_amdgcn_global_load_lds(
                    (const __attribute__((address_space(1))) unsigned int*)g,
                    (__attribute__((address_space(3))) unsigned int*)((char*)lB[0] + buf * 33280 + 128 * 256),
                    16, 0, 0);
        }
    };

    // prezero the (at most one) conv-padding row in both buffers
    if (l0 == 0 && tid < 64) { lB[0][tid] = 0.f; lB[1][tid] = 0.f; }
    if (l0 == 1920 && tid < 64) { lB[0][129 * 64 + tid] = 0.f; lB[1][129 * 64 + tid] = 0.f; }

    stageB(0, 0);
    __syncthreads();

    for (int iblk = 0; iblk < 8; ++iblk) {
        const int cur = iblk & 1;
        // ---- A fragments: direct global loads (issued first) ----
        half8 af[3][2][4];
#pragma unroll
        for (int kk = 0; kk < 3; ++kk)
#pragma unroll
            for (int ks = 0; ks < 2; ++ks)
#pragma unroll
                for (int mi = 0; mi < 4; ++mi)
                    af[kk][ks][mi] = *(const half8*)(Abase +
                        ((((size_t)iblk * 3 + kk) * 2 + ks) * 4 + mi) * 1024 + lane * 16);
        // ---- prefetch next B tile (completes by the end-of-iter barrier) ----
        if (iblk < 7) stageB(iblk + 1, cur ^ 1);
        // ---- compute: 96 MFMA from lB[cur] ----
        const char* bbase = (const char*)lB[cur];
#pragma unroll
        for (int kk = 0; kk < 3; ++kk) {
#pragma unroll
            for (int ks = 0; ks < 2; ++ks) {
                half8 bfr[4];
#pragma unroll
                for (int ni = 0; ni < 4; ++ni) {
                    const int rbuf = wn * 64 + ni * 16 + lane15 + kk;
                    const int key  = (rbuf + 15) & 15;
                    const int c2   = (ks * 4 + kgrp) << 1;
                    const f32x4 x = *(const f32x4*)(bbase + rbuf * 256 + ((c2 ^ key) << 4));
                    const f32x4 y = *(const f32x4*)(bbase + rbuf * 256 + (((c2 + 1) ^ key) << 4));
                    auto p0 = __builtin_amdgcn_cvt_pkrtz(x[0], x[1]);
                    auto p1 = __builtin_amdgcn_cvt_pkrtz(x[2], x[3]);
                    auto p2 = __builtin_amdgcn_cvt_pkrtz(y[0], y[1]);
                    auto p3 = __builtin_amdgcn_cvt_pkrtz(y[2], y[3]);
                    half8 hv;
                    hv[0] = p0[0]; hv[1] = p0[1]; hv[2] = p1[0]; hv[3] = p1[1];
                    hv[4] = p2[0]; hv[5] = p2[1]; hv[6] = p3[0]; hv[7] = p3[1];
                    bfr[ni] = hv;
                }
#pragma unroll
                for (int mi = 0; mi < 4; ++mi)
#pragma unroll
                    for (int ni = 0; ni < 4; ++ni)
                        acc[mi][ni] = __builtin_amdgcn_mfma_f32_16x16x32_f16(
                            af[kk][ks][mi], bfr[ni], acc[mi][ni], 0, 0, 0);
            }
        }
        __syncthreads();
    }

    // ---- epilogue ----
    const int mat = mblk >> 2;                         // 0=q 1=k 2=v
    const float* bias = (mat == 0) ? bq : (mat == 1) ? bk : bv;
    const int oBase = ((mblk & 3) << 7) + wm * 64 + kgrp * 4;
#pragma unroll
    for (int mi = 0; mi < 4; ++mi) {
#pragma unroll
        for (int r = 0; r < 4; ++r) {
            const int o = oBase + mi * 16 + r;         // channel within matrix
            const float bsv = bias[o];
            float vals[4];
            float mx = -3.0e38f;
#pragma unroll
            for (int ni = 0; ni < 4; ++ni) {
                float v = acc[mi][ni][r] + bsv;
                vals[ni] = v;
                mx = fmaxf(mx, v);
            }
#pragma unroll
            for (int d = 1; d < 16; d <<= 1) mx = fmaxf(mx, __shfl_xor(mx, d, 64));
            if (mat == 0) {
                if (lane15 == 0) atomicMax(&qmaxU[bb * U_ + o], fmap(mx));
            } else {
                __half* buf = (mat == 1) ? kbuf : vbuf;
                size_t rowbase = ((size_t)bb * U_ + o) * L_ + l0 + wn * 64;
#pragma unroll
                for (int ni = 0; ni < 4; ++ni)
                    buf[rowbase + ni * 16 + lane15] = __float2half(vals[ni]);
                unsigned* mptr = (mat == 1) ? kmaxU : vmaxU;
                if (lane15 == 0) atomicMax(&mptr[bb * U_ + o], fmap(mx));
            }
        }
    }
}

// ---------------------------------------------------------------------------
// Kernel 3: per-(b,h) attention, 1024 threads. k-pass: one aligned dword load
// + 2 shfl per thread-iter (edges scalar only at wave boundaries).
// ---------------------------------------------------------------------------
__global__ void __launch_bounds__(1024) attn_kernel(
    const __half* __restrict__ kbuf, const __half* __restrict__ vbuf,
    const unsigned* __restrict__ qmaxU, const unsigned* __restrict__ kmaxU,
    const unsigned* __restrict__ vmaxU,
    const int* __restrict__ g_mask, const int* __restrict__ t_mask,
    float* __restrict__ attout) {
    const int bh = blockIdx.x;
    const int b = bh >> 3, h = bh & 7;
    const int tid = threadIdx.x;
    const int lane = tid & 63;
    __shared__ float qs[64], kg[64], vg[64];
    __shared__ float pl[2048];
    __shared__ float red[1024];
    if (tid < 64) {
        qs[tid] = funmap(qmaxU[b * U_ + h * 64 + tid]);
        kg[tid] = funmap(kmaxU[b * U_ + h * 64 + tid]);
        vg[tid] = funmap(vmaxU[b * U_ + h * 64 + tid]);
    }
    __syncthreads();
    const float scale = 0.044194173824159216f;   // 1/sqrt(512)

    // logits for 2048 local (pooled) keys; thread owns 2 positions
    const __half* kbase = kbuf + ((size_t)b * U_ + h * 64) * L_;
    const int l0 = tid * 2;
    float acc0 = 0.f, acc1 = 0.f;
    for (int o = 0; o < 64; ++o) {
        const __half* row = kbase + (size_t)o * L_;
        const __half2 hv = *(const __half2*)(row + l0);
        float f1 = __half2float(hv.x), f2 = __half2float(hv.y);
        float fL = __shfl_up(f2, 1, 64);
        float fR = __shfl_down(f1, 1, 64);
        if (lane == 0)  fL = (l0 == 0) ? -3.0e38f : __half2float(row[l0 - 1]);
        if (lane == 63) fR = (l0 + 2 >= L_) ? -3.0e38f : __half2float(row[l0 + 2]);
        const float qw = qs[o];
        acc0 += qw * fmaxf(fL, fmaxf(f1, f2));
        acc1 += qw * fmaxf(f1, fmaxf(f2, fR));
    }
    float lmax = -3.0e38f;
    {
        int tm0 = t_mask[b * L_ + l0], tm1 = t_mask[b * L_ + l0 + 1];
        float lg0 = (tm0 == 0) ? -INFINITY : acc0 * scale;
        float lg1 = (tm1 == 0) ? -INFINITY : acc1 * scale;
        pl[l0] = lg0; pl[l0 + 1] = lg1;
        lmax = fmaxf(lg0, lg1);
    }
    // global-key logit (redundantly on all threads; cheap)
    float ag = 0.f;
    for (int d = 0; d < 64; ++d) ag += qs[d] * kg[d];
    const int gm = g_mask[b];
    float lgg = gm ? ag * scale : -INFINITY;
    // block max
    red[tid] = lmax; __syncthreads();
    for (int s = 512; s > 0; s >>= 1) {
        if (tid < s) red[tid] = fmaxf(red[tid], red[tid + s]);
        __syncthreads();
    }
    float mx = fmaxf(red[0], lgg);
    __syncthreads();
    // exponentials + denominator
    {
        float lg0 = pl[l0], lg1 = pl[l0 + 1];
        float e0 = (lg0 <= -3.0e38f) ? 0.f : __expf(lg0 - mx);
        float e1 = (lg1 <= -3.0e38f) ? 0.f : __expf(lg1 - mx);
        pl[l0] = e0; pl[l0 + 1] = e1;
        red[tid] = e0 + e1;
    }
    __syncthreads();
    for (int s = 512; s > 0; s >>= 1) {
        if (tid < s) red[tid] += red[tid + s];
        __syncthreads();
    }
    float eg = gm ? __expf(lgg - mx) : 0.f;
    float den = red[0] + eg;
    if (!(den > 0.f)) den = 1.f;
    __syncthreads();
    // weighted sum of pooled values: thread = (o = tid/16, 16 chunks of 128 l's)
    const int o = tid >> 4;
    const int ch = tid & 15;
    const __half* vrow = vbuf + ((size_t)b * U_ + h * 64 + o) * L_;
    float s = 0.f;
    for (int lb = ch * 128; lb < ch * 128 + 128; lb += 8) {
        union { uint4 u; __half hh[8]; } pk;
        pk.u = *(const uint4*)(vrow + lb);
        float f[10];
#pragma unroll
        for (int j = 0; j < 8; ++j) f[j + 1] = __half2float(pk.hh[j]);
        f[0] = (lb == 0) ? -3.0e38f : __half2float(vrow[lb - 1]);
        f[9] = (lb + 8 >= L_) ? -3.0e38f : __half2float(vrow[lb + 8]);
#pragma unroll
        for (int j = 0; j < 8; ++j)
            s += pl[lb + j] * fmaxf(f[j], fmaxf(f[j + 1], f[j + 2]));
    }
    red[tid] = s; __syncthreads();
    if (ch == 0) {
        float tot = 0.f;
#pragma unroll
        for (int q2 = 0; q2 < 16; ++q2) tot += red[(o << 4) + q2];
        float val = (eg * vg[o] + tot) / den;
        val *= (float)gm;
        attout[(size_t)b * U_ + h * 64 + o] = val;
    }
}

// ---------------------------------------------------------------------------
// Kernel 4: head mix (H x H) + output projection via WoT (coalesced)
// ---------------------------------------------------------------------------
__global__ void __launch_bounds__(512) out_kernel(
    const float* __restrict__ attout,
    const float* __restrict__ Wh, const float* __restrict__ bh,
    const float* __restrict__ WoT, const float* __restrict__ bo,
    float* __restrict__ out) {
    const int b = blockIdx.x;
    const int tid = threadIdx.x;
    __shared__ float tmp[512];
    const int oh = tid >> 6, d = tid & 63;
    float s = bh[oh];
#pragma unroll
    for (int i = 0; i < 8; ++i)
        s += Wh[oh * 8 + i] * attout[b * U_ + i * 64 + d];
    tmp[oh * 64 + d] = s;          // u = h*64 + d
    __syncthreads();
    float s2 = bo[tid];
    for (int i = 0; i < 512; ++i) s2 += WoT[i * 512 + tid] * tmp[i];
    out[b * U_ + tid] = s2;
}

// ---------------------------------------------------------------------------
extern "C" void kernel_launch(void* const* d_in, const int* in_sizes, int n_in,
                              void* d_out, int out_size, void* d_ws, size_t ws_size,
                              hipStream_t stream) {
    const float* t  = (const float*)d_in[0];
    // d_in[1] = g : unused by the reference
    const int* g_mask = (const int*)d_in[2];
    const int* t_mask = (const int*)d_in[3];
    const float* Wq = (const float*)d_in[4];
    const float* bq = (const float*)d_in[5];
    const float* Wk = (const float*)d_in[6];
    const float* bk = (const float*)d_in[7];
    const float* Wv = (const float*)d_in[8];
    const float* bv = (const float*)d_in[9];
    const float* Wh = (const float*)d_in[10];
    const float* bh = (const float*)d_in[11];
    const float* Wo = (const float*)d_in[12];
    const float* bo = (const float*)d_in[13];

    char* ws = (char*)d_ws;
    __half* Wrp2 = (__half*)ws;                                      // 4,718,592 B
    float* WoT   = (float*)(ws + 4718592);                           // 1,048,576 B
    __half* kbuf = (__half*)(ws + 5767168);                          // 67,108,864 B
    __half* vbuf = (__half*)(ws + 5767168 + 67108864);               // 67,108,864 B
    unsigned* qmaxU = (unsigned*)(ws + 5767168 + 2 * 67108864);
    unsigned* kmaxU = qmaxU + 16384;
    unsigned* vmaxU = kmaxU + 16384;
    float* attout = (float*)(vmaxU + 16384);

    (void)hipMemsetAsync(qmaxU, 0, 3 * 16384 * sizeof(unsigned), stream);
    repack_w2<<<1152, 256, 0, stream>>>(Wq, Wk, Wv, Wrp2);
    wot_repack<<<1024, 256, 0, stream>>>(Wo, WoT);
    conv_gemm<<<6144, 256, 0, stream>>>(t, Wrp2, bq, bk, bv, kbuf, vbuf,
                                        qmaxU, kmaxU, vmaxU);
    attn_kernel<<<256, 1024, 0, stream>>>(kbuf, vbuf, qmaxU, kmaxU, vmaxU,
                                          g_mask, t_mask, attout);
    out_kernel<<<32, 512, 0, stream>>>(attout, Wh, bh, WoT, bo, (float*)d_out);
}